// Round 4
// baseline (473.418 us; speedup 1.0000x reference)
//
#include <hip/hip_runtime.h>

// Bahdanau attention, MI355X. B=32, S=4096, D=U=512, fp32 in/out.
// R4 = R3 + LDS overflow fix: sbuf needs 8 waves * 64 rows * 4 B = 2048 B,
//     R3 allocated only 1024 -> waves 4..7 reduced through OOB LDS (absmax 7.8e-2).
// R3: persistent blocks (512 = 2/CU), 4 tiles each, 1-barrier-per-half-tile
//     software pipeline with chunked issue-early/write-late staging (T14),
//     hoisted epilogue constants, setprio around MFMA clusters (T5).
#define NB 32
#define NS 4096
#define ND 512
#define NU 512

typedef __attribute__((ext_vector_type(8))) __bf16 bf16x8;
typedef __attribute__((ext_vector_type(8))) short short8;
typedef __attribute__((ext_vector_type(4))) float f32x4;

union Cvt8 { __bf16 h[8]; short8 s8; };

__device__ __forceinline__ float fast_tanh(float x) {
  float e = __expf(2.0f * x);
  return 1.0f - __fdividef(2.0f, e + 1.0f);
}

// ---- K0a: pack W1 (f32 [D][U]) -> bf16 MFMA B-fragment order ----
__global__ void pack_w1_kernel(const float* __restrict__ W1, __bf16* __restrict__ W1f) {
  int idx = blockIdx.x * 256 + threadIdx.x;   // [16 ks][32 ct][64 lane]
  int l  = idx & 63;
  int ct = (idx >> 6) & 31;
  int ks = idx >> 11;
  int col   = ct * 16 + (l & 15);
  int kbase = ks * 32 + (l >> 4) * 8;
  Cvt8 u;
#pragma unroll
  for (int j = 0; j < 8; ++j) u.h[j] = (__bf16)W1[(size_t)(kbase + j) * NU + col];
  *reinterpret_cast<short8*>(W1f + (size_t)idx * 8) = u.s8;
}

// ---- K0b: pq[b][u] = query[b]@W2[:,u] + b2[u] + b1[u] ----
__global__ void proj_query_kernel(const float* __restrict__ query, const float* __restrict__ W2,
                                  const float* __restrict__ b2, const float* __restrict__ b1,
                                  float* __restrict__ pq) {
  int b = blockIdx.y;
  int u = blockIdx.x * 256 + threadIdx.x;
  const float* q = query + (size_t)b * ND;
  float acc = b2[u] + b1[u];
  for (int k = 0; k < ND; ++k) acc += q[k] * W2[(size_t)k * NU + u];
  pq[(size_t)b * NU + u] = acc;
}

// ---- K2: score[b][s] = sum_u tanh(values[b,s,:]@W1[:,u] + pq[b][u]) * V[u] ----
// Persistent: block g owns b = g>>4, s rows [(g&15)*256, +256) = 4 tiles of 64.
// 8 half-tiles (tile,khalf); LDS: 2 x 32 KB bf16 double-buffer (XOR-swizzled)
// + 2 KB reduce buffer. Pipeline: loads for half h+1 chunk-interleaved into
// MFMAs of half h; one barrier per half + one per epilogue.
__global__ __launch_bounds__(512, 4)
void score_kernel(const float* __restrict__ values, const __bf16* __restrict__ W1f,
                  const float* __restrict__ pq, const float* __restrict__ V,
                  float* __restrict__ scoreW) {
  __shared__ __align__(16) char ldsb[67584];  // 2x32KB dbuf + 2KB sbuf
  char* buf0 = ldsb;
  char* buf1 = ldsb + 32768;
  float* sbuf = (float*)(ldsb + 65536);       // [8 waves][64 rows] = 2048 B

  int g = blockIdx.x;                         // 512 = 32 b * 16 groups
  int b = g >> 4;
  int s0 = (g & 15) * 256;                    // 4 tiles * 64 rows
  int tid = threadIdx.x;
  int l = tid & 63;
  int w = tid >> 6;
  int lane_col = l & 15;
  int lane_k8  = l >> 4;

  // hoisted epilogue constants (same b for whole block)
  float pqv[4], Vv[4];
#pragma unroll
  for (int cf = 0; cf < 4; ++cf) {
    int col = w * 64 + cf * 16 + lane_col;
    pqv[cf] = pq[(size_t)b * NU + col];
    Vv[cf]  = V[col];
  }

  const float* vb0 = values + ((size_t)b * NS + s0) * ND;
  const __bf16* wptr = W1f + ((size_t)(w * 4) * 64 + l) * 8;

  // per-thread stage geometry: chunk c (0..3): idx = c*512+tid
  // row = idx>>5 (0..63), c8 = idx&31; 2 float4 (32 B fp32 -> 16 B bf16)
  float4 st[2];                               // one chunk in flight (8 VGPR)
  float4 st2[2];                              // second chunk in flight

  auto loadu = [&](float4* s, int tile, int kh, int c) {
    int idx = c * 512 + tid;
    int row = idx >> 5, c8 = idx & 31;
    const float4* p = reinterpret_cast<const float4*>(
        vb0 + (size_t)(tile * 64 + row) * ND + kh * 256 + c8 * 8);
    s[0] = p[0]; s[1] = p[1];
  };
  auto writeu = [&](const float4* s, char* dbuf, int c) {
    int idx = c * 512 + tid;
    int row = idx >> 5, c8 = idx & 31;
    Cvt8 u;
    u.h[0] = (__bf16)s[0].x; u.h[1] = (__bf16)s[0].y; u.h[2] = (__bf16)s[0].z; u.h[3] = (__bf16)s[0].w;
    u.h[4] = (__bf16)s[1].x; u.h[5] = (__bf16)s[1].y; u.h[6] = (__bf16)s[1].z; u.h[7] = (__bf16)s[1].w;
    int boff = row * 512 + ((c8 * 16) ^ ((row & 7) << 4));
    *reinterpret_cast<short8*>(dbuf + boff) = u.s8;
  };

  f32x4 acc[4][4];
#pragma unroll
  for (int rf = 0; rf < 4; ++rf)
#pragma unroll
    for (int cf = 0; cf < 4; ++cf) acc[rf][cf] = (f32x4){0.f, 0.f, 0.f, 0.f};

  // prologue: stage half 0 (tile 0, kh 0) into buf0
#pragma unroll
  for (int c = 0; c < 4; c += 2) {
    loadu(st, 0, 0, c); loadu(st2, 0, 0, c + 1);
    writeu(st, buf0, c); writeu(st2, buf0, c + 1);
  }

  // one ks step: 4 A-frags from LDS + 4 B-frags from L2 + 16 MFMA
  auto ksstep = [&](char* rbuf, int kg, int ks) {
    bf16x8 a[4];
    int kbyte = ks * 64 + lane_k8 * 16;
#pragma unroll
    for (int rf = 0; rf < 4; ++rf) {
      int row = rf * 16 + lane_col;
      a[rf] = *reinterpret_cast<const bf16x8*>(rbuf + row * 512 + (kbyte ^ ((row & 7) << 4)));
    }
    bf16x8 bb[4];
#pragma unroll
    for (int cf = 0; cf < 4; ++cf)
      bb[cf] = *reinterpret_cast<const bf16x8*>(wptr + (size_t)kg * 16384 + cf * 512);
    __builtin_amdgcn_s_setprio(1);
#pragma unroll
    for (int cf = 0; cf < 4; ++cf)
#pragma unroll
      for (int rf = 0; rf < 4; ++rf)
        acc[rf][cf] = __builtin_amdgcn_mfma_f32_16x16x32_bf16(a[rf], bb[cf], acc[rf][cf], 0, 0, 0);
    __builtin_amdgcn_s_setprio(0);
  };

  auto epilogue = [&](int tile) {
    float partial[4][4];
#pragma unroll
    for (int rf = 0; rf < 4; ++rf)
#pragma unroll
      for (int r = 0; r < 4; ++r) partial[rf][r] = 0.f;
#pragma unroll
    for (int cf = 0; cf < 4; ++cf)
#pragma unroll
      for (int rf = 0; rf < 4; ++rf)
#pragma unroll
        for (int r = 0; r < 4; ++r)
          partial[rf][r] += fast_tanh(acc[rf][cf][r] + pqv[cf]) * Vv[cf];
    // reduce over 16 lane_col lanes
#pragma unroll
    for (int off = 1; off < 16; off <<= 1)
#pragma unroll
      for (int rf = 0; rf < 4; ++rf)
#pragma unroll
        for (int r = 0; r < 4; ++r) partial[rf][r] += __shfl_xor(partial[rf][r], off);
    if (lane_col == 0) {
#pragma unroll
      for (int rf = 0; rf < 4; ++rf)
#pragma unroll
        for (int r = 0; r < 4; ++r)
          sbuf[w * 64 + rf * 16 + lane_k8 * 4 + r] = partial[rf][r];
    }
    __syncthreads();
    if (tid < 64) {
      float sc = 0.f;
#pragma unroll
      for (int wv = 0; wv < 8; ++wv) sc += sbuf[wv * 64 + tid];
      scoreW[(size_t)b * NS + s0 + tile * 64 + tid] = sc;
    }
    // re-zero accumulator for next tile
#pragma unroll
    for (int rf = 0; rf < 4; ++rf)
#pragma unroll
      for (int cf = 0; cf < 4; ++cf) acc[rf][cf] = (f32x4){0.f, 0.f, 0.f, 0.f};
  };

  for (int hp = 0; hp < 4; ++hp) {            // tile index
    // ---- even half h=2*hp: read buf0 (tile hp, kh 0); stage (hp, kh 1)->buf1
    __syncthreads();
    loadu(st, hp, 1, 0);
    ksstep(buf0, 0, 0);
    loadu(st2, hp, 1, 1);
    ksstep(buf0, 1, 1);
    writeu(st, buf1, 0);
    ksstep(buf0, 2, 2);
    loadu(st, hp, 1, 2);
    ksstep(buf0, 3, 3);
    writeu(st2, buf1, 1);
    ksstep(buf0, 4, 4);
    loadu(st2, hp, 1, 3);
    ksstep(buf0, 5, 5);
    writeu(st, buf1, 2);
    ksstep(buf0, 6, 6);
    ksstep(buf0, 7, 7);
    writeu(st2, buf1, 3);

    // ---- odd half h=2*hp+1: read buf1 (tile hp, kh 1); stage (hp+1, 0)->buf0
    __syncthreads();
    bool more = (hp < 3);
    if (more) loadu(st, hp + 1, 0, 0);
    ksstep(buf1, 8, 0);
    if (more) loadu(st2, hp + 1, 0, 1);
    ksstep(buf1, 9, 1);
    if (more) writeu(st, buf0, 0);
    ksstep(buf1, 10, 2);
    if (more) loadu(st, hp + 1, 0, 2);
    ksstep(buf1, 11, 3);
    if (more) writeu(st2, buf0, 1);
    ksstep(buf1, 12, 4);
    if (more) loadu(st2, hp + 1, 0, 3);
    ksstep(buf1, 13, 5);
    if (more) writeu(st, buf0, 2);
    ksstep(buf1, 14, 6);
    ksstep(buf1, 15, 7);
    if (more) writeu(st2, buf0, 3);

    epilogue(hp);
  }
}

// ---- K3: softmax over S per batch -> attention weights (d_out tail) ----
__global__ void softmax_kernel(const float* __restrict__ scoreW, float* __restrict__ attn) {
  int b = blockIdx.x, tid = threadIdx.x;      // 256 threads
  __shared__ float sred[8];
  const float* sc = scoreW + (size_t)b * NS;
  float m = -3.0e38f;
  for (int s = tid; s < NS; s += 256) m = fmaxf(m, sc[s]);
#pragma unroll
  for (int off = 1; off < 64; off <<= 1) m = fmaxf(m, __shfl_xor(m, off));
  if ((tid & 63) == 0) sred[tid >> 6] = m;
  __syncthreads();
  m = fmaxf(fmaxf(sred[0], sred[1]), fmaxf(sred[2], sred[3]));
  float sum = 0.f;
  for (int s = tid; s < NS; s += 256) sum += __expf(sc[s] - m);
#pragma unroll
  for (int off = 1; off < 64; off <<= 1) sum += __shfl_xor(sum, off);
  if ((tid & 63) == 0) sred[4 + (tid >> 6)] = sum;
  __syncthreads();
  float inv = 1.f / (sred[4] + sred[5] + sred[6] + sred[7]);
  float* ab = attn + (size_t)b * NS;
  for (int s = tid; s < NS; s += 256) ab[s] = __expf(sc[s] - m) * inv;
}

// ---- K4: context partials over 256-row chunks ----
__global__ void context_partial_kernel(const float* __restrict__ values,
                                       const float* __restrict__ attn,
                                       float* __restrict__ ctxpart) {
  int blk = blockIdx.x;                       // 32 b * 16 chunks
  int b = blk >> 4, c = blk & 15;
  int tid = threadIdx.x;                      // 256
  int t2 = tid & 127;
  int sg = tid >> 7;
  const float* vb = values + ((size_t)b * NS + c * 256) * ND;
  const float* ab = attn + (size_t)b * NS + c * 256;
  f32x4 acc = {0.f, 0.f, 0.f, 0.f};
  for (int s = sg; s < 256; s += 2) {
    float wv = ab[s];
    f32x4 v = *reinterpret_cast<const f32x4*>(vb + (size_t)s * ND + t2 * 4);
    acc += v * wv;
  }
  __shared__ f32x4 red[128];
  if (sg == 1) red[t2] = acc;
  __syncthreads();
  if (sg == 0) {
    acc += red[t2];
    *reinterpret_cast<f32x4*>(ctxpart + (size_t)blk * ND + t2 * 4) = acc;
  }
}

// ---- K5: reduce chunk partials -> context_vector (d_out head) ----
__global__ void context_reduce_kernel(const float* __restrict__ ctxpart, float* __restrict__ ctx) {
  int b = blockIdx.x, tid = threadIdx.x;      // 128 threads * float4
  f32x4 acc = {0.f, 0.f, 0.f, 0.f};
  for (int c = 0; c < 16; ++c)
    acc += *reinterpret_cast<const f32x4*>(ctxpart + (size_t)(b * 16 + c) * ND + tid * 4);
  *reinterpret_cast<f32x4*>(ctx + (size_t)b * ND + tid * 4) = acc;
}

extern "C" void kernel_launch(void* const* d_in, const int* in_sizes, int n_in,
                              void* d_out, int out_size, void* d_ws, size_t ws_size,
                              hipStream_t stream) {
  const float* query  = (const float*)d_in[0];
  const float* values = (const float*)d_in[1];
  const float* W1     = (const float*)d_in[2];
  const float* b1     = (const float*)d_in[3];
  const float* W2     = (const float*)d_in[4];
  const float* b2     = (const float*)d_in[5];
  const float* V      = (const float*)d_in[6];
  // d_in[7] = bv: softmax-invariant, score not an output: dropped.

  float* ctx_out  = (float*)d_out;            // [32][512]
  float* attn_out = ctx_out + NB * ND;        // [32][4096]

  char* ws = (char*)d_ws;
  __bf16* W1f    = (__bf16*)ws;               // 512 KB
  float*  pq     = (float*)(ws + 524288);     // 64 KB
  float*  scoreW = (float*)(ws + 589824);     // 512 KB
  float*  ctxp   = (float*)(ws + 1114112);    // 1 MB

  hipLaunchKernelGGL(pack_w1_kernel,        dim3(128),     dim3(256), 0, stream, W1, W1f);
  hipLaunchKernelGGL(proj_query_kernel,     dim3(2, NB),   dim3(256), 0, stream, query, W2, b2, b1, pq);
  hipLaunchKernelGGL(score_kernel,          dim3(512),     dim3(512), 0, stream, values, W1f, pq, V, scoreW);
  hipLaunchKernelGGL(softmax_kernel,        dim3(NB),      dim3(256), 0, stream, scoreW, attn_out);
  hipLaunchKernelGGL(context_partial_kernel,dim3(NB * 16), dim3(256), 0, stream, values, attn_out, ctxp);
  hipLaunchKernelGGL(context_reduce_kernel, dim3(NB),      dim3(128), 0, stream, ctxp, ctx_out);
}

// Round 5
// 200.620 us; speedup vs baseline: 2.3598x; 2.3598x over previous
//
#include <hip/hip_runtime.h>

// Bahdanau attention, MI355X. B=32, S=4096, D=U=512, fp32 in/out.
// R5: fix R4's register-spill disaster (WRITE_SIZE 297MB of scratch traffic).
//  - U-split (nb loop, K innermost over full-K 64KB LDS tile): acc 64->32 regs.
//  - Fragment-linear LDS layout: staging writes chunk c at byte c*16 (linear,
//    conflict-free), A-frag reads are lane-consecutive b128 (no swizzle).
//  - 2048 single-tile blocks; stage/compute overlap via 2-blocks/CU residency.
#define NB 32
#define NS 4096
#define ND 512
#define NU 512

typedef __attribute__((ext_vector_type(8))) __bf16 bf16x8;
typedef __attribute__((ext_vector_type(8))) short short8;
typedef __attribute__((ext_vector_type(4))) float f32x4;

union Cvt8 { __bf16 h[8]; short8 s8; };

__device__ __forceinline__ float fast_tanh(float x) {
  float e = __expf(2.0f * x);
  return 1.0f - __fdividef(2.0f, e + 1.0f);
}

// ---- K0a: pack W1 (f32 [D][U]) -> bf16 MFMA B-fragment order ----
// W1f[ks][ct][lane][j]: k = ks*32 + (lane>>4)*8 + j, u = ct*16 + (lane&15)
__global__ void pack_w1_kernel(const float* __restrict__ W1, __bf16* __restrict__ W1f) {
  int idx = blockIdx.x * 256 + threadIdx.x;   // [16 ks][32 ct][64 lane]
  int l  = idx & 63;
  int ct = (idx >> 6) & 31;
  int ks = idx >> 11;
  int col   = ct * 16 + (l & 15);
  int kbase = ks * 32 + (l >> 4) * 8;
  Cvt8 u;
#pragma unroll
  for (int j = 0; j < 8; ++j) u.h[j] = (__bf16)W1[(size_t)(kbase + j) * NU + col];
  *reinterpret_cast<short8*>(W1f + (size_t)idx * 8) = u.s8;
}

// ---- K0b: pq[b][u] = query[b]@W2[:,u] + b2[u] + b1[u] ----
__global__ void proj_query_kernel(const float* __restrict__ query, const float* __restrict__ W2,
                                  const float* __restrict__ b2, const float* __restrict__ b1,
                                  float* __restrict__ pq) {
  int b = blockIdx.y;
  int u = blockIdx.x * 256 + threadIdx.x;
  const float* q = query + (size_t)b * ND;
  float acc = b2[u] + b1[u];
  for (int k = 0; k < ND; ++k) acc += q[k] * W2[(size_t)k * NU + u];
  pq[(size_t)b * NU + u] = acc;
}

// ---- K2: score[b][s] = sum_u tanh(values[b,s,:]@W1[:,u] + pq[b][u]) * V[u] ----
// One 64-row tile per block, 8 waves. LDS tile in FRAGMENT-LINEAR order:
// chunk c (16B) at byte c*16; c = ((t*16+kg)*64 + lane); holds A-frag elems
// s = t*16 + (lane&15), k = kg*32 + (lane>>4)*8 + j. Wave w computes cols
// nb*256 + w*32 .. +32 for nb in {0,1} (U-split keeps acc at 32 regs).
__global__ __launch_bounds__(512, 4)
void score_kernel(const float* __restrict__ values, const __bf16* __restrict__ W1f,
                  const float* __restrict__ pq, const float* __restrict__ V,
                  float* __restrict__ scoreW) {
  __shared__ __align__(16) char ldsb[67584];  // 64KB tile + 2KB reduce buf
  float* sbuf = (float*)(ldsb + 65536);       // [8 waves][64 rows]

  int bid = blockIdx.x;                       // 2048 = 32 b * 64 tiles
  int b = bid >> 6;
  int s0 = (bid & 63) * 64;
  int tid = threadIdx.x;                      // 512
  int l = tid & 63;
  int w = tid >> 6;
  int lane_col = l & 15;
  int lane_k8  = l >> 4;

  // hoisted epilogue constants: 4 cols/thread = [nb][cf]
  float pqv[4], Vv[4];
#pragma unroll
  for (int nb = 0; nb < 2; ++nb)
#pragma unroll
    for (int cf = 0; cf < 2; ++cf) {
      int col = nb * 256 + w * 32 + cf * 16 + lane_col;
      pqv[nb * 2 + cf] = pq[(size_t)b * NU + col];
      Vv[nb * 2 + cf]  = V[col];
    }

  const float* vbase = values + ((size_t)b * NS + s0) * ND;

  // stage: 4096 16B chunks, 8 per thread. LDS linear; global decode per chunk.
  // Wave-level global pattern: 16 rows x 128B contiguous (coalesced 64B sectors).
#pragma unroll
  for (int i = 0; i < 8; ++i) {
    int c  = i * 512 + tid;
    int t  = c >> 10;
    int kg = (c >> 6) & 15;
    int ln = c & 63;
    int s  = t * 16 + (ln & 15);
    int c8 = kg * 4 + (ln >> 4);
    const float4* p = reinterpret_cast<const float4*>(vbase + (size_t)s * ND + c8 * 8);
    float4 f0 = p[0], f1 = p[1];
    Cvt8 u;
    u.h[0] = (__bf16)f0.x; u.h[1] = (__bf16)f0.y; u.h[2] = (__bf16)f0.z; u.h[3] = (__bf16)f0.w;
    u.h[4] = (__bf16)f1.x; u.h[5] = (__bf16)f1.y; u.h[6] = (__bf16)f1.z; u.h[7] = (__bf16)f1.w;
    *reinterpret_cast<short8*>(ldsb + (size_t)c * 16) = u.s8;
  }
  __syncthreads();

  float partial[4][4];                        // [t][r], carried across nb
#pragma unroll
  for (int t = 0; t < 4; ++t)
#pragma unroll
    for (int r = 0; r < 4; ++r) partial[t][r] = 0.f;

#pragma unroll
  for (int nb = 0; nb < 2; ++nb) {
    f32x4 acc[4][2];
#pragma unroll
    for (int t = 0; t < 4; ++t)
#pragma unroll
      for (int cf = 0; cf < 2; ++cf) acc[t][cf] = (f32x4){0.f, 0.f, 0.f, 0.f};

    // B-frag base for ct0 = nb*16 + w*2 (element units)
    const __bf16* wp = W1f + ((size_t)(nb * 16 + w * 2) * 64 + l) * 8;

    for (int kg = 0; kg < 16; ++kg) {
      bf16x8 a[4];
#pragma unroll
      for (int t = 0; t < 4; ++t)
        a[t] = *reinterpret_cast<const bf16x8*>(ldsb + (((t * 16 + kg) * 64 + l) << 4));
      bf16x8 bb[2];
#pragma unroll
      for (int cf = 0; cf < 2; ++cf)
        bb[cf] = *reinterpret_cast<const bf16x8*>(wp + (size_t)kg * 16384 + cf * 512);
      __builtin_amdgcn_s_setprio(1);
#pragma unroll
      for (int cf = 0; cf < 2; ++cf)
#pragma unroll
        for (int t = 0; t < 4; ++t)
          acc[t][cf] = __builtin_amdgcn_mfma_f32_16x16x32_bf16(a[t], bb[cf], acc[t][cf], 0, 0, 0);
      __builtin_amdgcn_s_setprio(0);
    }

    // fold this nb's cols into partial: tanh(proj + pq) * V
#pragma unroll
    for (int cf = 0; cf < 2; ++cf)
#pragma unroll
      for (int t = 0; t < 4; ++t)
#pragma unroll
        for (int r = 0; r < 4; ++r)
          partial[t][r] += fast_tanh(acc[t][cf][r] + pqv[nb * 2 + cf]) * Vv[nb * 2 + cf];
  }

  // reduce over the 16 lane_col lanes (cols), then across 8 waves via LDS
#pragma unroll
  for (int off = 1; off < 16; off <<= 1)
#pragma unroll
    for (int t = 0; t < 4; ++t)
#pragma unroll
      for (int r = 0; r < 4; ++r) partial[t][r] += __shfl_xor(partial[t][r], off);

  if (lane_col == 0) {
#pragma unroll
    for (int t = 0; t < 4; ++t)
#pragma unroll
      for (int r = 0; r < 4; ++r)
        sbuf[w * 64 + t * 16 + lane_k8 * 4 + r] = partial[t][r];
  }
  __syncthreads();
  if (tid < 64) {
    float sc = 0.f;
#pragma unroll
    for (int wv = 0; wv < 8; ++wv) sc += sbuf[wv * 64 + tid];
    scoreW[(size_t)b * NS + s0 + tid] = sc;   // bv omitted: softmax shift-invariant
  }
}

// ---- K3: softmax over S per batch -> attention weights (d_out tail) ----
__global__ void softmax_kernel(const float* __restrict__ scoreW, float* __restrict__ attn) {
  int b = blockIdx.x, tid = threadIdx.x;      // 256 threads
  __shared__ float sred[8];
  const float* sc = scoreW + (size_t)b * NS;
  float m = -3.0e38f;
  for (int s = tid; s < NS; s += 256) m = fmaxf(m, sc[s]);
#pragma unroll
  for (int off = 1; off < 64; off <<= 1) m = fmaxf(m, __shfl_xor(m, off));
  if ((tid & 63) == 0) sred[tid >> 6] = m;
  __syncthreads();
  m = fmaxf(fmaxf(sred[0], sred[1]), fmaxf(sred[2], sred[3]));
  float sum = 0.f;
  for (int s = tid; s < NS; s += 256) sum += __expf(sc[s] - m);
#pragma unroll
  for (int off = 1; off < 64; off <<= 1) sum += __shfl_xor(sum, off);
  if ((tid & 63) == 0) sred[4 + (tid >> 6)] = sum;
  __syncthreads();
  float inv = 1.f / (sred[4] + sred[5] + sred[6] + sred[7]);
  float* ab = attn + (size_t)b * NS;
  for (int s = tid; s < NS; s += 256) ab[s] = __expf(sc[s] - m) * inv;
}

// ---- K4: context partials over 256-row chunks ----
__global__ void context_partial_kernel(const float* __restrict__ values,
                                       const float* __restrict__ attn,
                                       float* __restrict__ ctxpart) {
  int blk = blockIdx.x;                       // 32 b * 16 chunks
  int b = blk >> 4, c = blk & 15;
  int tid = threadIdx.x;                      // 256
  int t2 = tid & 127;
  int sg = tid >> 7;
  const float* vb = values + ((size_t)b * NS + c * 256) * ND;
  const float* ab = attn + (size_t)b * NS + c * 256;
  f32x4 acc = {0.f, 0.f, 0.f, 0.f};
  for (int s = sg; s < 256; s += 2) {
    float wv = ab[s];
    f32x4 v = *reinterpret_cast<const f32x4*>(vb + (size_t)s * ND + t2 * 4);
    acc += v * wv;
  }
  __shared__ f32x4 red[128];
  if (sg == 1) red[t2] = acc;
  __syncthreads();
  if (sg == 0) {
    acc += red[t2];
    *reinterpret_cast<f32x4*>(ctxpart + (size_t)blk * ND + t2 * 4) = acc;
  }
}

// ---- K5: reduce chunk partials -> context_vector (d_out head) ----
__global__ void context_reduce_kernel(const float* __restrict__ ctxpart, float* __restrict__ ctx) {
  int b = blockIdx.x, tid = threadIdx.x;      // 128 threads * float4
  f32x4 acc = {0.f, 0.f, 0.f, 0.f};
  for (int c = 0; c < 16; ++c)
    acc += *reinterpret_cast<const f32x4*>(ctxpart + (size_t)(b * 16 + c) * ND + tid * 4);
  *reinterpret_cast<f32x4*>(ctx + (size_t)b * ND + tid * 4) = acc;
}

extern "C" void kernel_launch(void* const* d_in, const int* in_sizes, int n_in,
                              void* d_out, int out_size, void* d_ws, size_t ws_size,
                              hipStream_t stream) {
  const float* query  = (const float*)d_in[0];
  const float* values = (const float*)d_in[1];
  const float* W1     = (const float*)d_in[2];
  const float* b1     = (const float*)d_in[3];
  const float* W2     = (const float*)d_in[4];
  const float* b2     = (const float*)d_in[5];
  const float* V      = (const float*)d_in[6];
  // d_in[7] = bv: softmax-invariant, score not an output: dropped.

  float* ctx_out  = (float*)d_out;            // [32][512]
  float* attn_out = ctx_out + NB * ND;        // [32][4096]

  char* ws = (char*)d_ws;
  __bf16* W1f    = (__bf16*)ws;               // 512 KB
  float*  pq     = (float*)(ws + 524288);     // 64 KB
  float*  scoreW = (float*)(ws + 589824);     // 512 KB
  float*  ctxp   = (float*)(ws + 1114112);    // 1 MB

  hipLaunchKernelGGL(pack_w1_kernel,        dim3(128),     dim3(256), 0, stream, W1, W1f);
  hipLaunchKernelGGL(proj_query_kernel,     dim3(2, NB),   dim3(256), 0, stream, query, W2, b2, b1, pq);
  hipLaunchKernelGGL(score_kernel,          dim3(2048),    dim3(512), 0, stream, values, W1f, pq, V, scoreW);
  hipLaunchKernelGGL(softmax_kernel,        dim3(NB),      dim3(256), 0, stream, scoreW, attn_out);
  hipLaunchKernelGGL(context_partial_kernel,dim3(NB * 16), dim3(256), 0, stream, values, attn_out, ctxp);
  hipLaunchKernelGGL(context_reduce_kernel, dim3(NB),      dim3(128), 0, stream, ctxp, ctx_out);
}

// Round 6
// 196.965 us; speedup vs baseline: 2.4036x; 1.0186x over previous
//
#include <hip/hip_runtime.h>

// Bahdanau attention, MI355X. B=32, S=4096, D=U=512, fp32 in/out.
// R6 = R5 + ping-pong register prefetch in the kg loop (fully unrolled,
//     static parity indexing): kg+1's 4 ds_read_b128 + 2 B-frag L2 loads
//     issue before kg's MFMA cluster. Occupancy is LDS-capped (2 blocks/CU),
//     so the extra ~35 VGPR are free under __launch_bounds__(512,4).
// R5: U-split acc (32 regs), fragment-linear LDS (0 conflicts), no spills.
#define NB 32
#define NS 4096
#define ND 512
#define NU 512

typedef __attribute__((ext_vector_type(8))) __bf16 bf16x8;
typedef __attribute__((ext_vector_type(8))) short short8;
typedef __attribute__((ext_vector_type(4))) float f32x4;

union Cvt8 { __bf16 h[8]; short8 s8; };

__device__ __forceinline__ float fast_tanh(float x) {
  float e = __expf(2.0f * x);
  return 1.0f - __fdividef(2.0f, e + 1.0f);
}

// ---- K0a: pack W1 (f32 [D][U]) -> bf16 MFMA B-fragment order ----
// W1f[ks][ct][lane][j]: k = ks*32 + (lane>>4)*8 + j, u = ct*16 + (lane&15)
__global__ void pack_w1_kernel(const float* __restrict__ W1, __bf16* __restrict__ W1f) {
  int idx = blockIdx.x * 256 + threadIdx.x;   // [16 ks][32 ct][64 lane]
  int l  = idx & 63;
  int ct = (idx >> 6) & 31;
  int ks = idx >> 11;
  int col   = ct * 16 + (l & 15);
  int kbase = ks * 32 + (l >> 4) * 8;
  Cvt8 u;
#pragma unroll
  for (int j = 0; j < 8; ++j) u.h[j] = (__bf16)W1[(size_t)(kbase + j) * NU + col];
  *reinterpret_cast<short8*>(W1f + (size_t)idx * 8) = u.s8;
}

// ---- K0b: pq[b][u] = query[b]@W2[:,u] + b2[u] + b1[u] ----
__global__ void proj_query_kernel(const float* __restrict__ query, const float* __restrict__ W2,
                                  const float* __restrict__ b2, const float* __restrict__ b1,
                                  float* __restrict__ pq) {
  int b = blockIdx.y;
  int u = blockIdx.x * 256 + threadIdx.x;
  const float* q = query + (size_t)b * ND;
  float acc = b2[u] + b1[u];
  for (int k = 0; k < ND; ++k) acc += q[k] * W2[(size_t)k * NU + u];
  pq[(size_t)b * NU + u] = acc;
}

// ---- K2: score[b][s] = sum_u tanh(values[b,s,:]@W1[:,u] + pq[b][u]) * V[u] ----
// One 64-row tile per block, 8 waves. LDS tile in FRAGMENT-LINEAR order:
// chunk c (16B) at byte c*16; c = ((t*16+kg)*64 + lane); holds A-frag elems
// s = t*16 + (lane&15), k = kg*32 + (lane>>4)*8 + j. Wave w computes cols
// nb*256 + w*32 .. +32 for nb in {0,1} (U-split keeps acc at 32 regs).
__global__ __launch_bounds__(512, 4)
void score_kernel(const float* __restrict__ values, const __bf16* __restrict__ W1f,
                  const float* __restrict__ pq, const float* __restrict__ V,
                  float* __restrict__ scoreW) {
  __shared__ __align__(16) char ldsb[67584];  // 64KB tile + 2KB reduce buf
  float* sbuf = (float*)(ldsb + 65536);       // [8 waves][64 rows]

  int bid = blockIdx.x;                       // 2048 = 32 b * 64 tiles
  int b = bid >> 6;
  int s0 = (bid & 63) * 64;
  int tid = threadIdx.x;                      // 512
  int l = tid & 63;
  int w = tid >> 6;
  int lane_col = l & 15;
  int lane_k8  = l >> 4;

  // hoisted epilogue constants: 4 cols/thread = [nb][cf]
  float pqv[4], Vv[4];
#pragma unroll
  for (int nb = 0; nb < 2; ++nb)
#pragma unroll
    for (int cf = 0; cf < 2; ++cf) {
      int col = nb * 256 + w * 32 + cf * 16 + lane_col;
      pqv[nb * 2 + cf] = pq[(size_t)b * NU + col];
      Vv[nb * 2 + cf]  = V[col];
    }

  const float* vbase = values + ((size_t)b * NS + s0) * ND;

  // stage: 4096 16B chunks, 8 per thread. LDS linear; global decode per chunk.
#pragma unroll
  for (int i = 0; i < 8; ++i) {
    int c  = i * 512 + tid;
    int t  = c >> 10;
    int kg = (c >> 6) & 15;
    int ln = c & 63;
    int s  = t * 16 + (ln & 15);
    int c8 = kg * 4 + (ln >> 4);
    const float4* p = reinterpret_cast<const float4*>(vbase + (size_t)s * ND + c8 * 8);
    float4 f0 = p[0], f1 = p[1];
    Cvt8 u;
    u.h[0] = (__bf16)f0.x; u.h[1] = (__bf16)f0.y; u.h[2] = (__bf16)f0.z; u.h[3] = (__bf16)f0.w;
    u.h[4] = (__bf16)f1.x; u.h[5] = (__bf16)f1.y; u.h[6] = (__bf16)f1.z; u.h[7] = (__bf16)f1.w;
    *reinterpret_cast<short8*>(ldsb + (size_t)c * 16) = u.s8;
  }
  __syncthreads();

  float partial[4][4];                        // [t][r], carried across nb
#pragma unroll
  for (int t = 0; t < 4; ++t)
#pragma unroll
    for (int r = 0; r < 4; ++r) partial[t][r] = 0.f;

#pragma unroll
  for (int nb = 0; nb < 2; ++nb) {
    f32x4 acc[4][2];
#pragma unroll
    for (int t = 0; t < 4; ++t)
#pragma unroll
      for (int cf = 0; cf < 2; ++cf) acc[t][cf] = (f32x4){0.f, 0.f, 0.f, 0.f};

    // B-frag base for ct0 = nb*16 + w*2 (element units)
    const __bf16* wp = W1f + ((size_t)(nb * 16 + w * 2) * 64 + l) * 8;

    // ping-pong prefetch: issue kg+1 loads before kg's MFMA cluster
    bf16x8 aa[2][4];
    bf16x8 bbb[2][2];
#pragma unroll
    for (int t = 0; t < 4; ++t)
      aa[0][t] = *reinterpret_cast<const bf16x8*>(ldsb + (((t * 16 + 0) * 64 + l) << 4));
#pragma unroll
    for (int cf = 0; cf < 2; ++cf)
      bbb[0][cf] = *reinterpret_cast<const bf16x8*>(wp + (size_t)0 * 16384 + cf * 512);

#pragma unroll
    for (int kg = 0; kg < 16; ++kg) {
      const int cur = kg & 1, nxt = cur ^ 1;
      if (kg < 15) {
#pragma unroll
        for (int t = 0; t < 4; ++t)
          aa[nxt][t] = *reinterpret_cast<const bf16x8*>(ldsb + (((t * 16 + kg + 1) * 64 + l) << 4));
#pragma unroll
        for (int cf = 0; cf < 2; ++cf)
          bbb[nxt][cf] = *reinterpret_cast<const bf16x8*>(wp + (size_t)(kg + 1) * 16384 + cf * 512);
      }
      __builtin_amdgcn_s_setprio(1);
#pragma unroll
      for (int cf = 0; cf < 2; ++cf)
#pragma unroll
        for (int t = 0; t < 4; ++t)
          acc[t][cf] = __builtin_amdgcn_mfma_f32_16x16x32_bf16(aa[cur][t], bbb[cur][cf], acc[t][cf], 0, 0, 0);
      __builtin_amdgcn_s_setprio(0);
    }

    // fold this nb's cols into partial: tanh(proj + pq) * V
#pragma unroll
    for (int cf = 0; cf < 2; ++cf)
#pragma unroll
      for (int t = 0; t < 4; ++t)
#pragma unroll
        for (int r = 0; r < 4; ++r)
          partial[t][r] += fast_tanh(acc[t][cf][r] + pqv[nb * 2 + cf]) * Vv[nb * 2 + cf];
  }

  // reduce over the 16 lane_col lanes (cols), then across 8 waves via LDS
#pragma unroll
  for (int off = 1; off < 16; off <<= 1)
#pragma unroll
    for (int t = 0; t < 4; ++t)
#pragma unroll
      for (int r = 0; r < 4; ++r) partial[t][r] += __shfl_xor(partial[t][r], off);

  if (lane_col == 0) {
#pragma unroll
    for (int t = 0; t < 4; ++t)
#pragma unroll
      for (int r = 0; r < 4; ++r)
        sbuf[w * 64 + t * 16 + lane_k8 * 4 + r] = partial[t][r];
  }
  __syncthreads();
  if (tid < 64) {
    float sc = 0.f;
#pragma unroll
    for (int wv = 0; wv < 8; ++wv) sc += sbuf[wv * 64 + tid];
    scoreW[(size_t)b * NS + s0 + tid] = sc;   // bv omitted: softmax shift-invariant
  }
}

// ---- K3: softmax over S per batch -> attention weights (d_out tail) ----
__global__ void softmax_kernel(const float* __restrict__ scoreW, float* __restrict__ attn) {
  int b = blockIdx.x, tid = threadIdx.x;      // 256 threads
  __shared__ float sred[8];
  const float* sc = scoreW + (size_t)b * NS;
  float m = -3.0e38f;
  for (int s = tid; s < NS; s += 256) m = fmaxf(m, sc[s]);
#pragma unroll
  for (int off = 1; off < 64; off <<= 1) m = fmaxf(m, __shfl_xor(m, off));
  if ((tid & 63) == 0) sred[tid >> 6] = m;
  __syncthreads();
  m = fmaxf(fmaxf(sred[0], sred[1]), fmaxf(sred[2], sred[3]));
  float sum = 0.f;
  for (int s = tid; s < NS; s += 256) sum += __expf(sc[s] - m);
#pragma unroll
  for (int off = 1; off < 64; off <<= 1) sum += __shfl_xor(sum, off);
  if ((tid & 63) == 0) sred[4 + (tid >> 6)] = sum;
  __syncthreads();
  float inv = 1.f / (sred[4] + sred[5] + sred[6] + sred[7]);
  float* ab = attn + (size_t)b * NS;
  for (int s = tid; s < NS; s += 256) ab[s] = __expf(sc[s] - m) * inv;
}

// ---- K4: context partials over 256-row chunks ----
__global__ void context_partial_kernel(const float* __restrict__ values,
                                       const float* __restrict__ attn,
                                       float* __restrict__ ctxpart) {
  int blk = blockIdx.x;                       // 32 b * 16 chunks
  int b = blk >> 4, c = blk & 15;
  int tid = threadIdx.x;                      // 256
  int t2 = tid & 127;
  int sg = tid >> 7;
  const float* vb = values + ((size_t)b * NS + c * 256) * ND;
  const float* ab = attn + (size_t)b * NS + c * 256;
  f32x4 acc = {0.f, 0.f, 0.f, 0.f};
  for (int s = sg; s < 256; s += 2) {
    float wv = ab[s];
    f32x4 v = *reinterpret_cast<const f32x4*>(vb + (size_t)s * ND + t2 * 4);
    acc += v * wv;
  }
  __shared__ f32x4 red[128];
  if (sg == 1) red[t2] = acc;
  __syncthreads();
  if (sg == 0) {
    acc += red[t2];
    *reinterpret_cast<f32x4*>(ctxpart + (size_t)blk * ND + t2 * 4) = acc;
  }
}

// ---- K5: reduce chunk partials -> context_vector (d_out head) ----
__global__ void context_reduce_kernel(const float* __restrict__ ctxpart, float* __restrict__ ctx) {
  int b = blockIdx.x, tid = threadIdx.x;      // 128 threads * float4
  f32x4 acc = {0.f, 0.f, 0.f, 0.f};
  for (int c = 0; c < 16; ++c)
    acc += *reinterpret_cast<const f32x4*>(ctxpart + (size_t)(b * 16 + c) * ND + tid * 4);
  *reinterpret_cast<f32x4*>(ctx + (size_t)b * ND + tid * 4) = acc;
}

extern "C" void kernel_launch(void* const* d_in, const int* in_sizes, int n_in,
                              void* d_out, int out_size, void* d_ws, size_t ws_size,
                              hipStream_t stream) {
  const float* query  = (const float*)d_in[0];
  const float* values = (const float*)d_in[1];
  const float* W1     = (const float*)d_in[2];
  const float* b1     = (const float*)d_in[3];
  const float* W2     = (const float*)d_in[4];
  const float* b2     = (const float*)d_in[5];
  const float* V      = (const float*)d_in[6];
  // d_in[7] = bv: softmax-invariant, score not an output: dropped.

  float* ctx_out  = (float*)d_out;            // [32][512]
  float* attn_out = ctx_out + NB * ND;        // [32][4096]

  char* ws = (char*)d_ws;
  __bf16* W1f    = (__bf16*)ws;               // 512 KB
  float*  pq     = (float*)(ws + 524288);     // 64 KB
  float*  scoreW = (float*)(ws + 589824);     // 512 KB
  float*  ctxp   = (float*)(ws + 1114112);    // 1 MB

  hipLaunchKernelGGL(pack_w1_kernel,        dim3(128),     dim3(256), 0, stream, W1, W1f);
  hipLaunchKernelGGL(proj_query_kernel,     dim3(2, NB),   dim3(256), 0, stream, query, W2, b2, b1, pq);
  hipLaunchKernelGGL(score_kernel,          dim3(2048),    dim3(512), 0, stream, values, W1f, pq, V, scoreW);
  hipLaunchKernelGGL(softmax_kernel,        dim3(NB),      dim3(256), 0, stream, scoreW, attn_out);
  hipLaunchKernelGGL(context_partial_kernel,dim3(NB * 16), dim3(256), 0, stream, values, attn_out, ctxp);
  hipLaunchKernelGGL(context_reduce_kernel, dim3(NB),      dim3(128), 0, stream, ctxp, ctx_out);
}